// Round 5
// baseline (381.574 us; speedup 1.0000x reference)
//
#include <hip/hip_runtime.h>
#include <math.h>

#define Bb 512
#define Tt 512
#define Kk 128
#define NSTART 126   // K-2
#define NSTOP  127   // K-1
#define NTHR 128     // threads per block (2 waves)
#define RN 4         // next-state rows per thread
#define QS 4         // prev-state split factor
#define PW 32        // Kk/QS prev states per thread

static constexpr float LOG2E = 1.4426950408889634f;
static constexpr float LN2   = 0.6931471805599453f;

__device__ __forceinline__ float fexp2(float x) { return __builtin_amdgcn_exp2f(x); }
__device__ __forceinline__ float flog2(float x) { return __builtin_amdgcn_logf(x); }
__device__ __forceinline__ float frcp (float x) { return __builtin_amdgcn_rcpf(x); }

// s + quad_perm(s): VALU-only cross-lane add within the 4-lane quad (the q-group).
// dpp ctrl must be an ICE at the builtin call site -> template parameter.
template <int CTRL>
__device__ __forceinline__ float dpp_qp_add(float s) {
  union { float f; int i; } a, r;
  a.f = s;
  r.i = __builtin_amdgcn_update_dpp(a.i, a.i, CTRL, 0xf, 0xf, false);
  return s + r.f;
}
#define QP_XOR1 0xB1   // quad_perm [1,0,3,2]
#define QP_XOR2 0x4E   // quad_perm [2,3,0,1]

// One block per batch row; 128 threads: q = tid&3 (prev-quarter, 32 states),
// nb = tid>>2 (0..31) -> thread produces next-states nb+32r, r=0..3.
// Linear-space recursion a_new[n] = exp(feat[n]) * sum_p E[n,p] a[p].
// E = exp(trans) pinned in 128 VGPRs per thread.
// Alpha: LDS, double-buffered, 4 rotated copies (copy q stores alpha[p] at
// word (p-8q)&127) => thread reads words q*24+j (no wrap); the 4 concurrent
// b128 addresses hit bank-quads {0,24,16,8}+j -> conflict-free broadcasts.
// Renormalize block max -> 1 every 4 steps (growth <= ~1.3e7/step, 4 steps
// ~2.5e28 << fp32 max; underflow flushes only logsumexp-invisible terms).
__global__ __launch_bounds__(NTHR, 1) void crf_nll_lin3(
    const float* __restrict__ feats,   // [B,T,K]
    const int*   __restrict__ tags,    // [B,T]
    const float* __restrict__ trans,   // [K,K]  trans[next, prev]
    float* __restrict__ part)          // [B]
{
  const int b   = blockIdx.x;
  const int tid = threadIdx.x;
  const int q   = tid & 3;
  const int nb  = tid >> 2;       // 0..31
  const int w   = tid >> 6;       // wave id 0..1

  __shared__ __align__(16) float aL[2][QS][Kk];
  __shared__ float red[2];

  // ---- E rows in registers: E[r][j] = exp(trans[nb+32r, q*32+j]) ----
  float E[RN][PW];
  #pragma unroll
  for (int r = 0; r < RN; ++r) {
    const float* tr = trans + (size_t)(nb + 32*r) * Kk + q * PW;
    #pragma unroll
    for (int j = 0; j < PW; j += 4) {
      float4 v = *(const float4*)(tr + j);
      E[r][j+0] = fexp2(v.x * LOG2E);
      E[r][j+1] = fexp2(v.y * LOG2E);
      E[r][j+2] = fexp2(v.z * LOG2E);
      E[r][j+3] = fexp2(v.w * LOG2E);
    }
  }
  #pragma unroll
  for (int r = 0; r < RN; ++r)
    #pragma unroll
    for (int j = 0; j < PW; ++j)
      asm volatile("" : "+v"(E[r][j]));   // forbid rematerialization

  // write word indices for this thread's rows (rotated copy q)
  int wi[RN];
  #pragma unroll
  for (int r = 0; r < RN; ++r) wi[r] = ((nb + 32*r) - 8*q) & (Kk - 1);

  // ---- alpha0 (linear): 1 at START, 0 elsewhere ----
  #pragma unroll
  for (int r = 0; r < RN; ++r)
    aL[0][q][wi[r]] = ((nb + 32*r) == NSTART) ? 1.0f : 0.0f;
  __syncthreads();

  const float* fb = feats + (size_t)b * Tt * Kk;
  float C2 = 0.0f;                 // renorm offset, log2 units (uniform)
  float f[RN], fn[RN];
  #pragma unroll
  for (int r = 0; r < RN; ++r) f[r] = fb[nb + 32*r] * LOG2E;

  for (int t = 0; t < Tt; ++t) {
    const int cur = t & 1;
    if (t + 1 < Tt) {
      #pragma unroll
      for (int r = 0; r < RN; ++r)
        fn[r] = fb[(size_t)(t + 1) * Kk + nb + 32*r] * LOG2E;
    } else {
      #pragma unroll
      for (int r = 0; r < RN; ++r) fn[r] = 0.0f;
    }

    // 8 conflict-free b128 broadcast reads serve 128 fma (4 rows)
    const float* ap = &aL[cur][q][q * 24];
    float acc[RN][4];
    #pragma unroll
    for (int r = 0; r < RN; ++r)
      #pragma unroll
      for (int c = 0; c < 4; ++c) acc[r][c] = 0.0f;
    #pragma unroll
    for (int j4 = 0; j4 < PW/4; ++j4) {
      const float4 av = *(const float4*)(ap + 4*j4);
      #pragma unroll
      for (int r = 0; r < RN; ++r) {
        acc[r][0] = fmaf(E[r][4*j4+0], av.x, acc[r][0]);
        acc[r][1] = fmaf(E[r][4*j4+1], av.y, acc[r][1]);
        acc[r][2] = fmaf(E[r][4*j4+2], av.z, acc[r][2]);
        acc[r][3] = fmaf(E[r][4*j4+3], av.w, acc[r][3]);
      }
    }
    float y[RN];
    #pragma unroll
    for (int r = 0; r < RN; ++r) {
      float s = (acc[r][0] + acc[r][1]) + (acc[r][2] + acc[r][3]);
      s = dpp_qp_add<QP_XOR1>(s);      // + xor1 (VALU quad_perm)
      s = dpp_qp_add<QP_XOR2>(s);      // + xor2
      y[r] = fexp2(f[r]) * s;
    }

    if ((t & 3) == 3) {                // renormalize block max -> 1
      float m = fmaxf(fmaxf(y[0], y[1]), fmaxf(y[2], y[3]));
      m = fmaxf(m, __shfl_xor(m, 4, 64));
      m = fmaxf(m, __shfl_xor(m, 8, 64));
      m = fmaxf(m, __shfl_xor(m, 16, 64));
      m = fmaxf(m, __shfl_xor(m, 32, 64));
      if ((tid & 63) == 0) red[w] = m;
      __syncthreads();
      m = fmaxf(red[0], red[1]);
      C2 += flog2(m);
      const float inv = frcp(m);
      #pragma unroll
      for (int r = 0; r < RN; ++r) y[r] *= inv;
    }

    const int nxt = cur ^ 1;
    #pragma unroll
    for (int r = 0; r < RN; ++r) aL[nxt][q][wi[r]] = y[r];
    __syncthreads();
    #pragma unroll
    for (int r = 0; r < RN; ++r) f[r] = fn[r];
  }

  // ---- forward score: ln( sum_n a[n] * exp(T[STOP,n]) ) + offset ----
  // final alpha in buf0 (Tt even), copy 0 (rotation 0); NTHR == Kk.
  float v = aL[0][0][tid] * fexp2(trans[(size_t)NSTOP * Kk + tid] * LOG2E);
  #pragma unroll
  for (int off = 32; off >= 1; off >>= 1) v += __shfl_xor(v, off, 64);
  if ((tid & 63) == 0) red[w] = v;
  __syncthreads();
  const float fwd = LN2 * (C2 + flog2(red[0] + red[1]));

  // ---- gold path score (4 timesteps per thread) ----
  __syncthreads();                   // red reuse guard
  const int* tg = tags + (size_t)b * Tt;
  float g = 0.0f;
  #pragma unroll
  for (int k2 = 0; k2 < Tt / NTHR; ++k2) {
    const int tt   = tid + k2 * NTHR;
    const int curt = tg[tt];
    const int prv  = (tt == 0) ? NSTART : tg[tt - 1];
    g += trans[(size_t)curt * Kk + prv] + fb[(size_t)tt * Kk + curt];
  }
  if (tid == 0) g += trans[(size_t)NSTOP * Kk + tg[Tt - 1]];
  #pragma unroll
  for (int off = 32; off >= 1; off >>= 1) g += __shfl_xor(g, off, 64);
  if ((tid & 63) == 0) red[w] = g;
  __syncthreads();
  const float gold = red[0] + red[1];

  if (tid == 0) part[b] = fwd - gold;
}

__global__ __launch_bounds__(256) void reduce_mean_kernel(
    const float* __restrict__ part, float* __restrict__ out)
{
  __shared__ float buf[4];
  const int tid = threadIdx.x;
  float v = part[tid] + part[tid + 256];
  #pragma unroll
  for (int off = 32; off >= 1; off >>= 1) v += __shfl_xor(v, off, 64);
  if ((tid & 63) == 0) buf[tid >> 6] = v;
  __syncthreads();
  if (tid == 0)
    out[0] = (buf[0] + buf[1] + buf[2] + buf[3]) * (1.0f / (float)Bb);
}

extern "C" void kernel_launch(void* const* d_in, const int* in_sizes, int n_in,
                              void* d_out, int out_size, void* d_ws, size_t ws_size,
                              hipStream_t stream) {
  const float* feats = (const float*)d_in[0];
  const int*   tags  = (const int*)d_in[1];
  const float* trans = (const float*)d_in[2];
  float* part = (float*)d_ws;

  crf_nll_lin3<<<dim3(Bb), dim3(NTHR), 0, stream>>>(feats, tags, trans, part);
  reduce_mean_kernel<<<dim3(1), dim3(256), 0, stream>>>(part, (float*)d_out);
}

// Round 6
// 278.264 us; speedup vs baseline: 1.3713x; 1.3713x over previous
//
#include <hip/hip_runtime.h>
#include <math.h>

#define Bb 512
#define Tt 512
#define Kk 128
#define NSTART 126   // K-2
#define NSTOP  127   // K-1
#define NTHR 256     // threads per block (4 waves), one block per batch chain
#define PW 32        // prev states per thread (quarter)

static constexpr float LOG2E = 1.4426950408889634f;
static constexpr float LN2   = 0.6931471805599453f;

__device__ __forceinline__ float fexp2(float x) { return __builtin_amdgcn_exp2f(x); }
__device__ __forceinline__ float flog2(float x) { return __builtin_amdgcn_logf(x); }
__device__ __forceinline__ float frcp (float x) { return __builtin_amdgcn_rcpf(x); }

// s + quad_perm(s): VALU-only cross-lane add within the 4-lane quad (q-group).
template <int CTRL>
__device__ __forceinline__ float dpp_qp_add(float s) {
  union { float f; int i; } a, r;
  a.f = s;
  r.i = __builtin_amdgcn_update_dpp(a.i, a.i, CTRL, 0xf, 0xf, false);
  return s + r.f;
}
#define QP_XOR1 0xB1   // quad_perm [1,0,3,2]
#define QP_XOR2 0x4E   // quad_perm [2,3,0,1]

__device__ __forceinline__ float bf16lo(unsigned int d) {
  union { unsigned int u; float f; } v; v.u = d << 16;        return v.f;
}
__device__ __forceinline__ float bf16hi(unsigned int d) {
  union { unsigned int u; float f; } v; v.u = d & 0xFFFF0000u; return v.f;
}
__device__ __forceinline__ unsigned short to_bf16(float x) {
  union { float f; unsigned int u; } v; v.f = x;
  return (unsigned short)((v.u + 0x8000u) >> 16);             // round-half-up
}

// One block per batch chain; 256 threads: q = tid&3 (prev-quarter, 32 states),
// nb = tid>>2 (0..63) -> thread produces next-states nb and nb+64.
// Linear-space recursion a_new[n] = exp(feat[n]) * sum_p E[n,p] a[p].
// Alpha stored in LDS as bf16 (exponent range == fp32 -> same overflow math),
// single copy, double-buffered: thread q reads 4 x ds_read_b128 at words
// 16q+4j; address groups alias banks only 2-way (free). q-partials combined
// with DPP quad_perm adds (VALU, off the DS pipe).
// Renormalize block max -> 1 every 4 steps (growth <= ~1e6/step, 4 steps
// ~1e24 << fp32/bf16 max; underflow flushes only logsumexp-invisible terms).
__global__ __launch_bounds__(NTHR, 2) void crf_nll_bf16(
    const float* __restrict__ feats,   // [B,T,K]
    const int*   __restrict__ tags,    // [B,T]
    const float* __restrict__ trans,   // [K,K]  trans[next, prev]
    float* __restrict__ part)          // [B]
{
  const int b   = blockIdx.x;
  const int tid = threadIdx.x;
  const int q   = tid & 3;
  const int nb  = tid >> 2;       // 0..63
  const int w   = tid >> 6;       // wave id 0..3

  __shared__ __align__(16) unsigned int aU[2][Kk/2];  // bf16 pairs: word w = rows 2w,2w+1
  __shared__ float red[4];

  // ---- E rows in registers: E0[j]=exp(trans[nb,32q+j]), E1: row nb+64 ----
  float E0[PW], E1[PW];
  {
    const float* t0 = trans + (size_t)nb * Kk + q * PW;
    const float* t1 = trans + (size_t)(nb + 64) * Kk + q * PW;
    #pragma unroll
    for (int j = 0; j < PW; j += 4) {
      float4 v0 = *(const float4*)(t0 + j);
      float4 v1 = *(const float4*)(t1 + j);
      E0[j+0] = fexp2(v0.x * LOG2E);  E0[j+1] = fexp2(v0.y * LOG2E);
      E0[j+2] = fexp2(v0.z * LOG2E);  E0[j+3] = fexp2(v0.w * LOG2E);
      E1[j+0] = fexp2(v1.x * LOG2E);  E1[j+1] = fexp2(v1.y * LOG2E);
      E1[j+2] = fexp2(v1.z * LOG2E);  E1[j+3] = fexp2(v1.w * LOG2E);
    }
  }
  #pragma unroll
  for (int j = 0; j < PW; ++j)
    asm volatile("" : "+v"(E0[j]), "+v"(E1[j]));   // discourage remat

  // ---- alpha0: 1.0 at START (row 126 -> word 63 low half), else 0 ----
  if (tid < Kk/2) aU[0][tid] = (tid == 63) ? 0x00003F80u : 0u;
  __syncthreads();

  const float* fb = feats + (size_t)b * Tt * Kk;
  float C2 = 0.0f;                 // renorm offset, log2 units (uniform)
  float f0 = fb[nb] * LOG2E, f1 = fb[nb + 64] * LOG2E;

  for (int t = 0; t < Tt; ++t) {
    const int cur = t & 1;
    float f0n = 0.f, f1n = 0.f;
    if (t + 1 < Tt) {
      f0n = fb[(size_t)(t + 1) * Kk + nb] * LOG2E;
      f1n = fb[(size_t)(t + 1) * Kk + nb + 64] * LOG2E;
    }

    // 4 b128 reads = this thread's 32 prev states (bf16 pairs)
    const uint4* ap = (const uint4*)&aU[cur][q * (PW/2)];
    uint4 av[4];
    #pragma unroll
    for (int j4 = 0; j4 < 4; ++j4) av[j4] = ap[j4];

    float a0=0.f,a1=0.f,a2=0.f,a3=0.f, c0=0.f,c1=0.f,c2=0.f,c3=0.f;
    #pragma unroll
    for (int j4 = 0; j4 < 4; ++j4) {
      const unsigned int d[4] = { av[j4].x, av[j4].y, av[j4].z, av[j4].w };
      #pragma unroll
      for (int k = 0; k < 4; ++k) {
        const int j = j4*8 + k*2;          // prev-state pair base (local)
        const float lo = bf16lo(d[k]);
        const float hi = bf16hi(d[k]);
        a0 = fmaf(E0[j+0], lo, a0);
        a1 = fmaf(E0[j+1], hi, a1);
        c0 = fmaf(E1[j+0], lo, c0);
        c1 = fmaf(E1[j+1], hi, c1);
        // rotate accumulators to break chains
        { float tmp = a0; a0 = a2; a2 = tmp; }
        { float tmp = a1; a1 = a3; a3 = tmp; }
        { float tmp = c0; c0 = c2; c2 = tmp; }
        { float tmp = c1; c1 = c3; c3 = tmp; }
      }
    }
    float s0 = (a0 + a1) + (a2 + a3);
    float s1 = (c0 + c1) + (c2 + c3);
    s0 = dpp_qp_add<QP_XOR1>(s0);
    s0 = dpp_qp_add<QP_XOR2>(s0);
    s1 = dpp_qp_add<QP_XOR1>(s1);
    s1 = dpp_qp_add<QP_XOR2>(s1);
    float y0 = fexp2(f0) * s0;
    float y1 = fexp2(f1) * s1;

    if ((t & 3) == 3) {                // renormalize block max -> 1
      float m = fmaxf(y0, y1);         // q-lanes identical; reduce over nb bits
      m = fmaxf(m, __shfl_xor(m, 4, 64));
      m = fmaxf(m, __shfl_xor(m, 8, 64));
      m = fmaxf(m, __shfl_xor(m, 16, 64));
      m = fmaxf(m, __shfl_xor(m, 32, 64));
      if ((tid & 63) == 0) red[w] = m;
      __syncthreads();
      m = fmaxf(fmaxf(red[0], red[1]), fmaxf(red[2], red[3]));
      C2 += flog2(m);
      const float inv = frcp(m);
      y0 *= inv; y1 *= inv;
    }

    const int nxt = cur ^ 1;
    unsigned short* aH = (unsigned short*)&aU[nxt][0];
    if (q == 0) aH[nb]      = to_bf16(y0);
    if (q == 1) aH[nb + 64] = to_bf16(y1);
    __syncthreads();
    f0 = f0n; f1 = f1n;
  }

  // ---- forward score: ln( sum_n a[n] * exp(T[STOP,n]) ) + offset ----
  float v = 0.0f;
  if (tid < Kk) {
    const unsigned int d = aU[0][tid >> 1];
    const float an = (tid & 1) ? bf16hi(d) : bf16lo(d);
    v = an * fexp2(trans[(size_t)NSTOP * Kk + tid] * LOG2E);
  }
  #pragma unroll
  for (int off = 32; off >= 1; off >>= 1) v += __shfl_xor(v, off, 64);
  if ((tid & 63) == 0) red[w] = v;
  __syncthreads();
  const float S = (red[0] + red[1]) + (red[2] + red[3]);
  const float fwd = LN2 * (C2 + flog2(S));

  // ---- gold path score (2 timesteps per thread) ----
  __syncthreads();                   // red reuse guard
  const int* tg = tags + (size_t)b * Tt;
  float g = 0.0f;
  #pragma unroll
  for (int k2 = 0; k2 < Tt / NTHR; ++k2) {
    const int tt   = tid + k2 * NTHR;
    const int curt = tg[tt];
    const int prv  = (tt == 0) ? NSTART : tg[tt - 1];
    g += trans[(size_t)curt * Kk + prv] + fb[(size_t)tt * Kk + curt];
  }
  if (tid == 0) g += trans[(size_t)NSTOP * Kk + tg[Tt - 1]];
  #pragma unroll
  for (int off = 32; off >= 1; off >>= 1) g += __shfl_xor(g, off, 64);
  if ((tid & 63) == 0) red[w] = g;
  __syncthreads();
  const float gold = (red[0] + red[1]) + (red[2] + red[3]);

  if (tid == 0) part[b] = fwd - gold;
}

__global__ __launch_bounds__(256) void reduce_mean_kernel(
    const float* __restrict__ part, float* __restrict__ out)
{
  __shared__ float buf[4];
  const int tid = threadIdx.x;
  float v = part[tid] + part[tid + 256];
  #pragma unroll
  for (int off = 32; off >= 1; off >>= 1) v += __shfl_xor(v, off, 64);
  if ((tid & 63) == 0) buf[tid >> 6] = v;
  __syncthreads();
  if (tid == 0)
    out[0] = (buf[0] + buf[1] + buf[2] + buf[3]) * (1.0f / (float)Bb);
}

extern "C" void kernel_launch(void* const* d_in, const int* in_sizes, int n_in,
                              void* d_out, int out_size, void* d_ws, size_t ws_size,
                              hipStream_t stream) {
  const float* feats = (const float*)d_in[0];
  const int*   tags  = (const int*)d_in[1];
  const float* trans = (const float*)d_in[2];
  float* part = (float*)d_ws;

  crf_nll_bf16<<<dim3(Bb), dim3(NTHR), 0, stream>>>(feats, tags, trans, part);
  reduce_mean_kernel<<<dim3(1), dim3(256), 0, stream>>>(part, (float*)d_out);
}

// Round 7
// 229.158 us; speedup vs baseline: 1.6651x; 1.2143x over previous
//
#include <hip/hip_runtime.h>
#include <math.h>

#define Bb 512
#define Tt 512
#define Kk 128
#define NSTART 126   // K-2
#define NSTOP  127   // K-1
#define NTHR 256     // threads per block (4 waves), one block per batch chain
#define PW 32        // prev states per thread (quarter)

static constexpr float LOG2E = 1.4426950408889634f;
static constexpr float LN2   = 0.6931471805599453f;

__device__ __forceinline__ float fexp2(float x) { return __builtin_amdgcn_exp2f(x); }
__device__ __forceinline__ float flog2(float x) { return __builtin_amdgcn_logf(x); }
__device__ __forceinline__ float frcp (float x) { return __builtin_amdgcn_rcpf(x); }

// packed-bf16 dot2: d = a.lo*b.lo + a.hi*b.hi + c   (V_DOT2_F32_BF16, VOP3P)
__device__ __forceinline__ float dot2bf(unsigned int a, unsigned int b, float c) {
  float d;
  asm("v_dot2_f32_bf16 %0, %1, %2, %3" : "=v"(d) : "v"(a), "v"(b), "v"(c));
  return d;
}

// s + quad_perm(s): VALU-only cross-lane add within the 4-lane quad (q-group).
template <int CTRL>
__device__ __forceinline__ float dpp_qp_add(float s) {
  union { float f; int i; } a, r;
  a.f = s;
  r.i = __builtin_amdgcn_update_dpp(a.i, a.i, CTRL, 0xf, 0xf, false);
  return s + r.f;
}
#define QP_XOR1 0xB1   // quad_perm [1,0,3,2]
#define QP_XOR2 0x4E   // quad_perm [2,3,0,1]

__device__ __forceinline__ unsigned short to_bf16(float x) {
  union { float f; unsigned int u; } v; v.f = x;
  return (unsigned short)((v.u + 0x8000u) >> 16);             // round-half-up
}
__device__ __forceinline__ float bf16lo(unsigned int d) {
  union { unsigned int u; float f; } v; v.u = d << 16;        return v.f;
}
__device__ __forceinline__ float bf16hi(unsigned int d) {
  union { unsigned int u; float f; } v; v.u = d & 0xFFFF0000u; return v.f;
}

// One block per batch chain; 256 threads: q = tid&3 (prev-quarter, 32 states),
// nb = tid>>2 (0..63) -> thread produces next-states nb and nb+64.
// Linear-space recursion a_new[n] = exp(feat[n]) * sum_p E[n,p] a[p].
// E = exp(trans) as PACKED bf16 pairs: 16 dwords per row, 32 per thread.
// Alpha in LDS as bf16 pairs (halfword p = row p), double-buffered; thread q
// reads 4 x ds_read_b128 (its 32 prev states); 2-way bank alias only (free).
// Inner product via v_dot2_f32_bf16 (no unpack); q-partials combined with
// DPP quad_perm adds (VALU). Renormalize block max -> 1 every 4 steps
// (bf16 range == fp32, growth <= ~1e24 over 4 steps << 3e38).
__global__ __launch_bounds__(NTHR, 2) void crf_nll_dot(
    const float* __restrict__ feats,   // [B,T,K]
    const int*   __restrict__ tags,    // [B,T]
    const float* __restrict__ trans,   // [K,K]  trans[next, prev]
    float* __restrict__ part)          // [B]
{
  const int b   = blockIdx.x;
  const int tid = threadIdx.x;
  const int q   = tid & 3;
  const int nb  = tid >> 2;       // 0..63
  const int w   = tid >> 6;       // wave id 0..3

  __shared__ __align__(16) unsigned int aW[2][Kk/2];  // bf16 pairs: word w = rows 2w,2w+1
  __shared__ float red[4];

  // ---- E rows, packed bf16 pairs: E0[j] = {exp(tr[nb,32q+2j]), exp(tr[nb,32q+2j+1])} ----
  unsigned int E0[16], E1[16];
  {
    const float* t0 = trans + (size_t)nb * Kk + q * PW;
    const float* t1 = trans + (size_t)(nb + 64) * Kk + q * PW;
    #pragma unroll
    for (int j = 0; j < 16; ++j) {
      float2 v0 = *(const float2*)(t0 + 2*j);
      float2 v1 = *(const float2*)(t1 + 2*j);
      E0[j] = ((unsigned int)to_bf16(fexp2(v0.y * LOG2E)) << 16) | to_bf16(fexp2(v0.x * LOG2E));
      E1[j] = ((unsigned int)to_bf16(fexp2(v1.y * LOG2E)) << 16) | to_bf16(fexp2(v1.x * LOG2E));
    }
  }
  #pragma unroll
  for (int j = 0; j < 16; ++j)
    asm volatile("" : "+v"(E0[j]), "+v"(E1[j]));   // keep resident, no remat

  // ---- alpha0: 1.0 at START (row 126 -> word 63 lo half), else 0 ----
  if (tid < Kk/2) aW[0][tid] = (tid == 63) ? 0x00003F80u : 0u;
  __syncthreads();

  const float* fb = feats + (size_t)b * Tt * Kk;
  float C2 = 0.0f;                 // renorm offset, log2 units (uniform)
  float f0 = fb[nb] * LOG2E, f1 = fb[nb + 64] * LOG2E;

  for (int t = 0; t < Tt; ++t) {
    const int cur = t & 1;
    float f0n = 0.f, f1n = 0.f;
    if (t + 1 < Tt) {
      f0n = fb[(size_t)(t + 1) * Kk + nb] * LOG2E;
      f1n = fb[(size_t)(t + 1) * Kk + nb + 64] * LOG2E;
    }

    // 4 b128 reads = this thread's 32 prev states (bf16 pairs, 16 dwords)
    const uint4* ap = (const uint4*)&aW[cur][q * 16];
    uint4 av[4];
    #pragma unroll
    for (int j4 = 0; j4 < 4; ++j4) av[j4] = ap[j4];

    // 16 dot2 per row, 4 accumulator chains per row
    float a0=0.f,a1=0.f,a2=0.f,a3=0.f, c0=0.f,c1=0.f,c2=0.f,c3=0.f;
    #pragma unroll
    for (int j4 = 0; j4 < 4; ++j4) {
      a0 = dot2bf(E0[4*j4+0], av[j4].x, a0);
      a1 = dot2bf(E0[4*j4+1], av[j4].y, a1);
      a2 = dot2bf(E0[4*j4+2], av[j4].z, a2);
      a3 = dot2bf(E0[4*j4+3], av[j4].w, a3);
      c0 = dot2bf(E1[4*j4+0], av[j4].x, c0);
      c1 = dot2bf(E1[4*j4+1], av[j4].y, c1);
      c2 = dot2bf(E1[4*j4+2], av[j4].z, c2);
      c3 = dot2bf(E1[4*j4+3], av[j4].w, c3);
    }
    float s0 = (a0 + a1) + (a2 + a3);
    float s1 = (c0 + c1) + (c2 + c3);
    s0 = dpp_qp_add<QP_XOR1>(s0);
    s0 = dpp_qp_add<QP_XOR2>(s0);
    s1 = dpp_qp_add<QP_XOR1>(s1);
    s1 = dpp_qp_add<QP_XOR2>(s1);
    float y0 = fexp2(f0) * s0;     // full sums in all quad lanes
    float y1 = fexp2(f1) * s1;

    if ((t & 3) == 3) {            // renormalize block max -> 1
      float m = fmaxf(y0, y1);     // quad-uniform; reduce across nb groups
      m = fmaxf(m, __shfl_xor(m, 4, 64));
      m = fmaxf(m, __shfl_xor(m, 8, 64));
      m = fmaxf(m, __shfl_xor(m, 16, 64));
      m = fmaxf(m, __shfl_xor(m, 32, 64));
      if ((tid & 63) == 0) red[w] = m;
      __syncthreads();
      m = fmaxf(fmaxf(red[0], red[1]), fmaxf(red[2], red[3]));
      C2 += flog2(m);
      const float inv = frcp(m);
      y0 *= inv; y1 *= inv;
    }

    const int nxt = cur ^ 1;
    unsigned short* aH = (unsigned short*)&aW[nxt][0];
    if (q == 0) aH[nb]      = to_bf16(y0);
    if (q == 1) aH[nb + 64] = to_bf16(y1);
    __syncthreads();
    f0 = f0n; f1 = f1n;
  }

  // ---- forward score: ln( sum_n a[n] * exp(T[STOP,n]) ) + offset ----
  float v = 0.0f;
  if (tid < Kk) {
    const unsigned int d = aW[0][tid >> 1];
    const float an = (tid & 1) ? bf16hi(d) : bf16lo(d);
    v = an * fexp2(trans[(size_t)NSTOP * Kk + tid] * LOG2E);
  }
  #pragma unroll
  for (int off = 32; off >= 1; off >>= 1) v += __shfl_xor(v, off, 64);
  if ((tid & 63) == 0) red[w] = v;
  __syncthreads();
  const float S = (red[0] + red[1]) + (red[2] + red[3]);
  const float fwd = LN2 * (C2 + flog2(S));

  // ---- gold path score (2 timesteps per thread) ----
  __syncthreads();                   // red reuse guard
  const int* tg = tags + (size_t)b * Tt;
  float g = 0.0f;
  #pragma unroll
  for (int k2 = 0; k2 < Tt / NTHR; ++k2) {
    const int tt   = tid + k2 * NTHR;
    const int curt = tg[tt];
    const int prv  = (tt == 0) ? NSTART : tg[tt - 1];
    g += trans[(size_t)curt * Kk + prv] + fb[(size_t)tt * Kk + curt];
  }
  if (tid == 0) g += trans[(size_t)NSTOP * Kk + tg[Tt - 1]];
  #pragma unroll
  for (int off = 32; off >= 1; off >>= 1) g += __shfl_xor(g, off, 64);
  if ((tid & 63) == 0) red[w] = g;
  __syncthreads();
  const float gold = (red[0] + red[1]) + (red[2] + red[3]);

  if (tid == 0) part[b] = fwd - gold;
}

__global__ __launch_bounds__(256) void reduce_mean_kernel(
    const float* __restrict__ part, float* __restrict__ out)
{
  __shared__ float buf[4];
  const int tid = threadIdx.x;
  float v = part[tid] + part[tid + 256];
  #pragma unroll
  for (int off = 32; off >= 1; off >>= 1) v += __shfl_xor(v, off, 64);
  if ((tid & 63) == 0) buf[tid >> 6] = v;
  __syncthreads();
  if (tid == 0)
    out[0] = (buf[0] + buf[1] + buf[2] + buf[3]) * (1.0f / (float)Bb);
}

extern "C" void kernel_launch(void* const* d_in, const int* in_sizes, int n_in,
                              void* d_out, int out_size, void* d_ws, size_t ws_size,
                              hipStream_t stream) {
  const float* feats = (const float*)d_in[0];
  const int*   tags  = (const int*)d_in[1];
  const float* trans = (const float*)d_in[2];
  float* part = (float*)d_ws;

  crf_nll_dot<<<dim3(Bb), dim3(NTHR), 0, stream>>>(feats, tags, trans, part);
  reduce_mean_kernel<<<dim3(1), dim3(256), 0, stream>>>(part, (float*)d_out);
}